// Round 1
// baseline (539.293 us; speedup 1.0000x reference)
//
#include <hip/hip_runtime.h>
#include <hip/hip_bf16.h>
#include <cstdint>

// I/O is FP32. Derivation: c=DT=0.1, d=1+DT/EPS=11; layer out = (-u,-v):
//   V = [vr | rhsu] @ Bcat^T, Bcat = [Minv | 0.1*(Minv W^T)] (1024x2048),
//   u_raw = 0.1 V W^T = AC @ Ccat^T, Ccat = 0.1*W@Bcat = [0.1*P | 0.01*P@W^T],
//   P = W@Minv;  un = u_raw - u_in - 0.1 b;  AC_next = [10relu(un)-V | un+0.1b'],
//   Minv = (I - (0.01/11) W^T W)/11  (Neumann, trunc err ~1.5e-6).
// R7: gemm_layer ported to the 8-phase counted-vmcnt template (T2+T3+T4+T5):
//   BM=256 BN=128 BK=64, 512 thr (8 waves), dual accumulators, 128KB LDS,
//   XOR-16B-slot swizzle (inverse-swz global source + swz read), raw
//   s_barrier + vmcnt(2) counted waits (never drained mid-loop), setprio(1)
//   around the MFMA cluster. 4 phases/K-tile, 16 MFMA/phase.

typedef __bf16 bf16;
typedef __bf16 bf16x4 __attribute__((ext_vector_type(4)));
typedef __bf16 bf16x8 __attribute__((ext_vector_type(8)));
typedef float  f32x4  __attribute__((ext_vector_type(4)));

#define C_DT    0.1f
#define C_DTEPS 10.0f
#define C_DINV  (1.0f/11.0f)
#define C_MSC   (0.01f/121.0f)

__device__ __forceinline__ void async_load16(const bf16* g, bf16* l) {
    __builtin_amdgcn_global_load_lds(
        (__attribute__((address_space(1))) void*)(g),
        (__attribute__((address_space(3))) void*)(l),
        16, 0, 0);
}

// XCD-aware remap for (8,64) grids: per-XCD L2 working set ~ row-panel + B.
__device__ __forceinline__ void remap_block(int& bx, int& by) {
    if (gridDim.y == 64) {
        const int lin  = by * 8 + bx;
        const int xcd  = lin & 7;
        const int slot = lin >> 3;
        by = xcd * 8 + (slot & 7);
        bx = slot >> 3;
    }
}

// ---------------------------------------------------------------------------
// C = A @ B^T (A: MxK ld lda, B: NxK ld ldb, bf16). 128x128 tile, BK=32,
// double-buffered, batched over blockIdx.z.
// EPI 0 Z0   : t=a+e1[n]; out_f=t; out_b1=11*relu(t); out_b2=t+0.1*e2[n]
// EPI 1 MINV : v=(m==n?1/11:0)-C_MSC*a; out_b1=v; out_b2=v
// EPI 2 SCALE: out_b1 = sgn*a; if(out_b2) out_b2 = 0.1*sgn*a
// EPI 5 ULAST: un=sgn*a-e0[m*ldf+n]-0.1*e1[n]; out_b1=hi(un); out_b2=lo(un)
// ---------------------------------------------------------------------------
template<int EPI>
__global__ __launch_bounds__(256, 2)
void gemm_bt(const bf16* __restrict__ A, const bf16* __restrict__ B,
             float* __restrict__ out_f,
             bf16* __restrict__ out_b1, bf16* __restrict__ out_b2,
             const float* __restrict__ e0, const float* __restrict__ e1,
             const float* __restrict__ e2,
             int M, int N, int K, int lda, int ldb,
             int ldf, int ld1, int ld2, float sgn,
             long zsA, long zsB, long zs1, long zs2)
{
    __shared__ __attribute__((aligned(16))) char smem[32768];
    bf16* sAe = (bf16*)smem;             // 2 x 4096 elements
    bf16* sBe = (bf16*)(smem + 16384);

    const int t    = threadIdx.x;
    const int wave = t >> 6;
    const int lane = t & 63;
    int bx = blockIdx.x, by = blockIdx.y;
    remap_block(bx, by);
    const long zb = blockIdx.z;
    A += zb * zsA;
    B += zb * zsB;
    if (out_b1) out_b1 += zb * zs1;
    if (out_b2) out_b2 += zb * zs2;

    const long row0 = (long)by * 128;
    const long col0 = (long)bx * 128;
    const int wr = wave >> 1, wc = wave & 1;

    f32x4 acc[4][4];
#pragma unroll
    for (int i = 0; i < 4; i++)
#pragma unroll
        for (int j = 0; j < 4; j++)
            acc[i][j] = f32x4{0.f, 0.f, 0.f, 0.f};

    const int  q  = t >> 2;
    const int  gp = ((t & 3) + 4 - ((q + (q >> 2)) & 3)) & 3;
    const bf16* gA = A + (row0 + q) * (long)lda + gp * 8;
    const bf16* gB = B + (col0 + q) * (long)ldb + gp * 8;

    const int l15  = lane & 15;
    const int fch  = ((lane >> 4) + l15 + (l15 >> 2)) & 3;
    const int aoff = (wr * 64 + l15) * 32 + fch * 8;
    const int boff = (wc * 64 + l15) * 32 + fch * 8;

    auto stage = [&](int buf, int k0) {
        bf16* dA = sAe + buf * 4096 + wave * 512;
        bf16* dB = sBe + buf * 4096 + wave * 512;
        async_load16(gA + k0,                     dA);
        async_load16(gA + 64 * (long)lda + k0,    dA + 2048);
        async_load16(gB + k0,                     dB);
        async_load16(gB + 64 * (long)ldb + k0,    dB + 2048);
    };

    const int nIter = K >> 5;
    stage(0, 0);
    __syncthreads();
    for (int k = 0; k < nIter; k++) {
        const int cur = k & 1;
        if (k + 1 < nIter) stage(cur ^ 1, (k + 1) << 5);

        bf16x8 af[4], bfv[4];
#pragma unroll
        for (int i = 0; i < 4; i++)
            af[i] = *(const bf16x8*)(sAe + cur * 4096 + aoff + i * 16 * 32);
#pragma unroll
        for (int j = 0; j < 4; j++)
            bfv[j] = *(const bf16x8*)(sBe + cur * 4096 + boff + j * 16 * 32);
#pragma unroll
        for (int i = 0; i < 4; i++)
#pragma unroll
            for (int j = 0; j < 4; j++)
                acc[i][j] = __builtin_amdgcn_mfma_f32_16x16x32_bf16(
                    af[i], bfv[j], acc[i][j], 0, 0, 0);

        __syncthreads();
    }

    float* epi = (float*)smem + wave * 1024;
    const int wbase = (lane >> 4) * 256 + (l15 >> 2) * 4 + (l15 & 3);

#pragma unroll
    for (int i = 0; i < 4; i++) {
#pragma unroll
        for (int j = 0; j < 4; j++)
#pragma unroll
            for (int r = 0; r < 4; r++)
                epi[wbase + r * 64 + 16 * j] = acc[i][j][r];

#pragma unroll
        for (int qq = 0; qq < 4; qq++) {
            const f32x4 a4 = ((const f32x4*)epi)[qq * 64 + lane];
            const long m = row0 + wr * 64 + i * 16 + qq * 4 + (lane >> 4);
            const long n = col0 + wc * 64 + 4 * l15;

            if (EPI == 0) {
                const f32x4 b1 = *(const f32x4*)(e1 + n);
                const f32x4 b2 = *(const f32x4*)(e2 + n);
                f32x4 tv; bf16x4 rv, hv;
#pragma unroll
                for (int e = 0; e < 4; e++) {
                    tv[e] = a4[e] + b1[e];
                    rv[e] = (bf16)(11.f * fmaxf(tv[e], 0.f));
                    hv[e] = (bf16)(tv[e] + C_DT * b2[e]);
                }
                *(f32x4*)(out_f + m * (long)ldf + n)    = tv;
                *(bf16x4*)(out_b1 + m * (long)ld1 + n)  = rv;
                *(bf16x4*)(out_b2 + m * (long)ld2 + n)  = hv;
            } else if (EPI == 1) {
                bf16x4 ov;
#pragma unroll
                for (int e = 0; e < 4; e++)
                    ov[e] = (bf16)(((m == n + e) ? C_DINV : 0.f) - C_MSC * a4[e]);
                *(bf16x4*)(out_b1 + m * (long)ld1 + n) = ov;
                *(bf16x4*)(out_b2 + m * (long)ld2 + n) = ov;
            } else if (EPI == 2) {
                bf16x4 ov, o2;
#pragma unroll
                for (int e = 0; e < 4; e++) {
                    ov[e] = (bf16)(sgn * a4[e]);
                    o2[e] = (bf16)(C_DT * sgn * a4[e]);
                }
                *(bf16x4*)(out_b1 + m * (long)ld1 + n) = ov;
                if (out_b2) *(bf16x4*)(out_b2 + m * (long)ld2 + n) = o2;
            } else {  // EPI 5
                const f32x4 u0 = *(const f32x4*)(e0 + m * (long)ldf + n);
                const f32x4 b1 = *(const f32x4*)(e1 + n);
                bf16x4 hv, lv;
#pragma unroll
                for (int e = 0; e < 4; e++) {
                    float un = sgn * a4[e] - u0[e] - C_DT * b1[e];
                    bf16 h = (bf16)un;
                    hv[e] = h;
                    lv[e] = (bf16)(un - (float)h);
                }
                *(bf16x4*)(out_b1 + m * (long)ld1 + n) = hv;
                *(bf16x4*)(out_b2 + m * (long)ld2 + n) = lv;
            }
        }
    }
}

// ---------------------------------------------------------------------------
// Fused layer, 8-phase counted-vmcnt schedule.
// accV = AC@Bcat^T, accU = AC@Ccat^T (K=2048) in one block.
// BM=256 BN=128 BK=64; 8 waves (2Mx4N), per-wave 128x32 per accumulator.
// LDS layout (bf16 elems): A[2][4 chunks][64x64] @0, B1[2][2][64x64] @32768,
// B2[2][2][64x64] @49152. Chunk = 64 rows x 64 cols, 16B-slot XOR swizzle
// (slot ^= row&7) realized via inverse-swizzled global source (linear
// global_load_lds dest) + matching XOR on ds_read addresses.
// Per K-tile: 4 phases (row-half rh x k-half kh): 16 MFMA each.
// Stage (next tile): p1 A0,A2 | p2 B1_0,B1_1 | p3 B2_0,B2_1 | p4 A1,A3.
// Waits: vmcnt(2) before p1 (oldest 6 = A0,A2,B1*,B2*), vmcnt(2) before p2
// (oldest 2 = A1,A3). Last tile drains vmcnt(0) at p1.
// Epilogue: un = accU - u - 0.1*bl;  u <- un (in-place);
//           ACo[:, :1024] = 10*relu(un) - accV;  ACo[:, 1024:] = un + 0.1*bn.
// ---------------------------------------------------------------------------
__global__ __launch_bounds__(512, 2)
void gemm_layer8(const bf16* __restrict__ A, const bf16* __restrict__ B1,
                 const bf16* __restrict__ B2, float* __restrict__ u,
                 bf16* __restrict__ ACo,
                 const float* __restrict__ bl, const float* __restrict__ bn)
{
    __shared__ __attribute__((aligned(16))) bf16 sm[65536];   // 128 KiB

    const int t    = threadIdx.x;
    const int wave = t >> 6;
    const int lane = t & 63;
    const int l15  = lane & 15;
    const int lq   = lane >> 4;
    const int bx = blockIdx.x;         // N/128 = 8 (xcd = lin%8 = bx: B-slice L2-hot)
    const int by = blockIdx.y;         // M/256 = 32
    const long row0 = (long)by * 256;
    const long col0 = (long)bx * 128;
    const int wr = wave >> 2;          // 0..1 (M half)
    const int wc = wave & 3;           // 0..3 (N quarter)

    f32x4 accV[8][2], accU[8][2];
#pragma unroll
    for (int i = 0; i < 8; i++)
#pragma unroll
        for (int j = 0; j < 2; j++) {
            accV[i][j] = f32x4{0.f, 0.f, 0.f, 0.f};
            accU[i][j] = f32x4{0.f, 0.f, 0.f, 0.f};
        }

    // staging: thread t covers chunk byte [t*16, t*16+16) (linear LDS dest);
    // row r = t>>3, phys slot s = t&7 holds logical slot s^(r&7) -> fetch
    // global col-group sg = (t&7)^((t>>3)&7).
    const int tr = t >> 3;
    const int sg = (t & 7) ^ (tr & 7);
    const bf16* gA  = A  + (row0 + tr) * 2048 + sg * 8;
    const bf16* gB1 = B1 + (col0 + tr) * 2048 + sg * 8;
    const bf16* gB2 = B2 + (col0 + tr) * 2048 + sg * 8;
    bf16* const ldA  = sm + wave * 512;          // + buf*16384 + ci*4096
    bf16* const ldB1 = sm + 32768 + wave * 512;  // + buf*8192  + cb*4096
    bf16* const ldB2 = sm + 49152 + wave * 512;

    auto stA = [&](int buf, int ci, int k0) {
        async_load16(gA + (long)ci * 131072 + k0, ldA + buf * 16384 + ci * 4096);
    };
    auto stB1v = [&](int buf, int cb, int k0) {
        async_load16(gB1 + (long)cb * 131072 + k0, ldB1 + buf * 8192 + cb * 4096);
    };
    auto stB2v = [&](int buf, int cb, int k0) {
        async_load16(gB2 + (long)cb * 131072 + k0, ldB2 + buf * 8192 + cb * 4096);
    };

    // read addressing: logical (row rr, k-group q=kh*4+lq) -> phys slot q^(rr&7)
    const int sl0 = lq ^ (l15 & 7);          // kh=0
    const int sl1 = (4 + lq) ^ (l15 & 7);    // kh=1
    const int aro = l15 * 64;                // + ci*4096 + fi*1024 + sl*8
    const int cbo = (wc >> 1) * 4096;
    const int bro = ((wc & 1) * 32 + l15) * 64;

    // prologue: tile 0, issue order A0,A2,B1_0,B1_1,B2_0,B2_1,A1,A3
    stA(0, 0, 0); stA(0, 2, 0);
    stB1v(0, 0, 0); stB1v(0, 1, 0);
    stB2v(0, 0, 0); stB2v(0, 1, 0);
    stA(0, 1, 0); stA(0, 3, 0);

    for (int kt = 0; kt < 32; ++kt) {
        const int  cur = kt & 1, nb = cur ^ 1;
        const bool st  = kt < 31;
        const int  k0n = (kt + 1) << 6;
        const bf16* bA  = sm + cur * 16384;
        const bf16* bB1 = sm + 32768 + cur * 8192;
        const bf16* bB2 = sm + 49152 + cur * 8192;
        bf16x8 a[4], b1k[2], b2k[2];

        // ---- phase 1: rh=0, kh=0 ----
        if (st) asm volatile("s_waitcnt vmcnt(2)" ::: "memory");
        else    asm volatile("s_waitcnt vmcnt(0)" ::: "memory");
        __builtin_amdgcn_s_barrier();
#pragma unroll
        for (int fi = 0; fi < 4; ++fi)
            a[fi] = *(const bf16x8*)(bA + wr * 8192 + fi * 1024 + aro + sl0 * 8);
#pragma unroll
        for (int fj = 0; fj < 2; ++fj) {
            b1k[fj] = *(const bf16x8*)(bB1 + cbo + fj * 1024 + bro + sl0 * 8);
            b2k[fj] = *(const bf16x8*)(bB2 + cbo + fj * 1024 + bro + sl0 * 8);
        }
        if (st) { stA(nb, 0, k0n); stA(nb, 2, k0n); }
        __builtin_amdgcn_s_barrier();
        asm volatile("s_waitcnt lgkmcnt(0)" ::: "memory");
        __builtin_amdgcn_s_setprio(1);
#pragma unroll
        for (int fi = 0; fi < 4; ++fi)
#pragma unroll
            for (int fj = 0; fj < 2; ++fj) {
                accV[fi][fj] = __builtin_amdgcn_mfma_f32_16x16x32_bf16(
                    a[fi], b1k[fj], accV[fi][fj], 0, 0, 0);
                accU[fi][fj] = __builtin_amdgcn_mfma_f32_16x16x32_bf16(
                    a[fi], b2k[fj], accU[fi][fj], 0, 0, 0);
            }
        __builtin_amdgcn_s_setprio(0);

        // ---- phase 2: rh=1, kh=0 (needs A1,A3 of this tile) ----
        asm volatile("s_waitcnt vmcnt(2)" ::: "memory");
        __builtin_amdgcn_s_barrier();
#pragma unroll
        for (int fi = 0; fi < 4; ++fi)
            a[fi] = *(const bf16x8*)(bA + wr * 8192 + 4096 + fi * 1024 + aro + sl0 * 8);
        if (st) { stB1v(nb, 0, k0n); stB1v(nb, 1, k0n); }
        __builtin_amdgcn_s_barrier();
        asm volatile("s_waitcnt lgkmcnt(0)" ::: "memory");
        __builtin_amdgcn_s_setprio(1);
#pragma unroll
        for (int fi = 0; fi < 4; ++fi)
#pragma unroll
            for (int fj = 0; fj < 2; ++fj) {
                accV[4 + fi][fj] = __builtin_amdgcn_mfma_f32_16x16x32_bf16(
                    a[fi], b1k[fj], accV[4 + fi][fj], 0, 0, 0);
                accU[4 + fi][fj] = __builtin_amdgcn_mfma_f32_16x16x32_bf16(
                    a[fi], b2k[fj], accU[4 + fi][fj], 0, 0, 0);
            }
        __builtin_amdgcn_s_setprio(0);

        // ---- phase 3: rh=0, kh=1 ----
        __builtin_amdgcn_s_barrier();
#pragma unroll
        for (int fi = 0; fi < 4; ++fi)
            a[fi] = *(const bf16x8*)(bA + wr * 8192 + fi * 1024 + aro + sl1 * 8);
#pragma unroll
        for (int fj = 0; fj < 2; ++fj) {
            b1k[fj] = *(const bf16x8*)(bB1 + cbo + fj * 1024 + bro + sl1 * 8);
            b2k[fj] = *(const bf16x8*)(bB2 + cbo + fj * 1024 + bro + sl1 * 8);
        }
        if (st) { stB2v(nb, 0, k0n); stB2v(nb, 1, k0n); }
        __builtin_amdgcn_s_barrier();
        asm volatile("s_waitcnt lgkmcnt(0)" ::: "memory");
        __builtin_amdgcn_s_setprio(1);
#pragma unroll
        for (int fi = 0; fi < 4; ++fi)
#pragma unroll
            for (int fj = 0; fj < 2; ++fj) {
                accV[fi][fj] = __builtin_amdgcn_mfma_f32_16x16x32_bf16(
                    a[fi], b1k[fj], accV[fi][fj], 0, 0, 0);
                accU[fi][fj] = __builtin_amdgcn_mfma_f32_16x16x32_bf16(
                    a[fi], b2k[fj], accU[fi][fj], 0, 0, 0);
            }
        __builtin_amdgcn_s_setprio(0);

        // ---- phase 4: rh=1, kh=1 ----
        __builtin_amdgcn_s_barrier();
#pragma unroll
        for (int fi = 0; fi < 4; ++fi)
            a[fi] = *(const bf16x8*)(bA + wr * 8192 + 4096 + fi * 1024 + aro + sl1 * 8);
        if (st) { stA(nb, 1, k0n); stA(nb, 3, k0n); }
        __builtin_amdgcn_s_barrier();
        asm volatile("s_waitcnt lgkmcnt(0)" ::: "memory");
        __builtin_amdgcn_s_setprio(1);
#pragma unroll
        for (int fi = 0; fi < 4; ++fi)
#pragma unroll
            for (int fj = 0; fj < 2; ++fj) {
                accV[4 + fi][fj] = __builtin_amdgcn_mfma_f32_16x16x32_bf16(
                    a[fi], b1k[fj], accV[4 + fi][fj], 0, 0, 0);
                accU[4 + fi][fj] = __builtin_amdgcn_mfma_f32_16x16x32_bf16(
                    a[fi], b2k[fj], accU[4 + fi][fj], 0, 0, 0);
            }
        __builtin_amdgcn_s_setprio(0);
    }

    // Epilogue: per-wave private 1024-float scratch at sm[0..32KB) (= buf0 A
    // region; tile 31 read buf1 only, all ds_reads drained by per-phase lgkm).
    // Handles two row-frags (32x32 block) per round; V then U through the
    // same region (same-wave DS ops are in-order).
    float* epi = (float*)sm + wave * 1024;
    const int ew = lq * 128 + l15;     // row=(lq*4+r), col=l15: idx = (lq*4)*32 + l15

#pragma unroll
    for (int fib = 0; fib < 4; ++fib) {
#pragma unroll
        for (int f2 = 0; f2 < 2; ++f2)
#pragma unroll
            for (int fj = 0; fj < 2; ++fj)
#pragma unroll
                for (int r = 0; r < 4; ++r)
                    epi[f2 * 512 + ew + r * 32 + fj * 16] = accV[fib * 2 + f2][fj][r];
        f32x4 v4[4];
#pragma unroll
        for (int qq = 0; qq < 4; ++qq)
            v4[qq] = ((const f32x4*)epi)[qq * 64 + lane];
#pragma unroll
        for (int f2 = 0; f2 < 2; ++f2)
#pragma unroll
            for (int fj = 0; fj < 2; ++fj)
#pragma unroll
                for (int r = 0; r < 4; ++r)
                    epi[f2 * 512 + ew + r * 32 + fj * 16] = accU[fib * 2 + f2][fj][r];

#pragma unroll
        for (int qq = 0; qq < 4; ++qq) {
            const f32x4 a4 = ((const f32x4*)epi)[qq * 64 + lane];
            const long m = row0 + wr * 128 + fib * 32 + qq * 8 + (lane >> 3);
            const long n = col0 + wc * 32 + (lane & 7) * 4;
            const long iu = m * 1024 + n;
            const f32x4 u0 = *(const f32x4*)(u + iu);
            const f32x4 c1 = *(const f32x4*)(bl + n);
            const f32x4 c2 = *(const f32x4*)(bn + n);
            f32x4 un; bf16x4 rv, hv;
#pragma unroll
            for (int e = 0; e < 4; ++e) {
                un[e] = a4[e] - u0[e] - C_DT * c1[e];
                rv[e] = (bf16)(C_DTEPS * fmaxf(un[e], 0.f) - v4[qq][e]);
                hv[e] = (bf16)(un[e] + C_DT * c2[e]);
            }
            *(f32x4*)(u + iu) = un;
            *(bf16x4*)(ACo + m * 2048 + n)        = rv;
            *(bf16x4*)(ACo + m * 2048 + 1024 + n) = hv;
        }
    }
}

// logits = (Ah+Al)@(Bh+Bl)^T + bias (3-term), fp32 out, double-buffered.
__global__ __launch_bounds__(256, 2)
void gemm_split(const bf16* __restrict__ Ah, const bf16* __restrict__ Al,
                const bf16* __restrict__ Bh, const bf16* __restrict__ Bl,
                float* __restrict__ out, const float* __restrict__ bias,
                int M, int N, int K, int blim)
{
    __shared__ __attribute__((aligned(16))) char smem[65536];
    bf16* sAh = (bf16*)smem;
    bf16* sAl = (bf16*)(smem + 16384);
    bf16* sBh = (bf16*)(smem + 32768);
    bf16* sBl = (bf16*)(smem + 49152);

    const int t    = threadIdx.x;
    const int wave = t >> 6;
    const int lane = t & 63;
    int bx = blockIdx.x, by = blockIdx.y;
    remap_block(bx, by);
    const long row0 = (long)by * 128;
    const long col0 = (long)bx * 128;
    const int wr = wave >> 1, wc = wave & 1;

    f32x4 acc[4][4];
#pragma unroll
    for (int i = 0; i < 4; i++)
#pragma unroll
        for (int j = 0; j < 4; j++)
            acc[i][j] = f32x4{0.f, 0.f, 0.f, 0.f};

    const int  q  = t >> 2;
    const int  gp = ((t & 3) + 4 - ((q + (q >> 2)) & 3)) & 3;
    const long gao = (row0 + q) * (long)K + gp * 8;
    const long gbo = (col0 + q) * (long)K + gp * 8;

    const int l15  = lane & 15;
    const int fch  = ((lane >> 4) + l15 + (l15 >> 2)) & 3;
    const int aoff = (wr * 64 + l15) * 32 + fch * 8;
    const int boff = (wc * 64 + l15) * 32 + fch * 8;

    auto stage = [&](int buf, int k0) {
        const int d = buf * 4096 + wave * 512;
        async_load16(Ah + gao + k0,                 sAh + d);
        async_load16(Ah + gao + 64 * (long)K + k0,  sAh + d + 2048);
        async_load16(Al + gao + k0,                 sAl + d);
        async_load16(Al + gao + 64 * (long)K + k0,  sAl + d + 2048);
        async_load16(Bh + gbo + k0,                 sBh + d);
        async_load16(Bh + gbo + 64 * (long)K + k0,  sBh + d + 2048);
        async_load16(Bl + gbo + k0,                 sBl + d);
        async_load16(Bl + gbo + 64 * (long)K + k0,  sBl + d + 2048);
    };

    const int nIter = K >> 5;
    stage(0, 0);
    __syncthreads();
    for (int k = 0; k < nIter; k++) {
        const int cur = k & 1;
        if (k + 1 < nIter) stage(cur ^ 1, (k + 1) << 5);

        bf16x8 ah[4], al[4], bh[4], bl[4];
#pragma unroll
        for (int i = 0; i < 4; i++) {
            ah[i] = *(const bf16x8*)(sAh + cur * 4096 + aoff + i * 16 * 32);
            al[i] = *(const bf16x8*)(sAl + cur * 4096 + aoff + i * 16 * 32);
        }
#pragma unroll
        for (int j = 0; j < 4; j++) {
            bh[j] = *(const bf16x8*)(sBh + cur * 4096 + boff + j * 16 * 32);
            bl[j] = *(const bf16x8*)(sBl + cur * 4096 + boff + j * 16 * 32);
        }
#pragma unroll
        for (int i = 0; i < 4; i++)
#pragma unroll
            for (int j = 0; j < 4; j++) {
                acc[i][j] = __builtin_amdgcn_mfma_f32_16x16x32_bf16(
                    ah[i], bh[j], acc[i][j], 0, 0, 0);
                acc[i][j] = __builtin_amdgcn_mfma_f32_16x16x32_bf16(
                    ah[i], bl[j], acc[i][j], 0, 0, 0);
                acc[i][j] = __builtin_amdgcn_mfma_f32_16x16x32_bf16(
                    al[i], bh[j], acc[i][j], 0, 0, 0);
            }
        __syncthreads();
    }

    float* epi = (float*)smem + wave * 1024;
    const int wbase = (lane >> 4) * 256 + (l15 >> 2) * 4 + (l15 & 3);

#pragma unroll
    for (int i = 0; i < 4; i++) {
#pragma unroll
        for (int j = 0; j < 4; j++)
#pragma unroll
            for (int r = 0; r < 4; r++)
                epi[wbase + r * 64 + 16 * j] = acc[i][j][r];

#pragma unroll
        for (int qq = 0; qq < 4; qq++) {
            f32x4 a4 = ((const f32x4*)epi)[qq * 64 + lane];
            const long m = row0 + wr * 64 + i * 16 + qq * 4 + (lane >> 4);
            const long n = col0 + wc * 64 + 4 * l15;
            f32x4 bv = f32x4{0.f, 0.f, 0.f, 0.f};
            if (n < blim) bv = *(const f32x4*)(bias + n);
#pragma unroll
            for (int e = 0; e < 4; e++) a4[e] += bv[e];
            *(f32x4*)(out + m * (long)N + n) = a4;
        }
    }
}

// fp32 -> bf16 for x (16384 blocks) and W_in (2048 blocks) in one dispatch
__global__ void conv_xw(const float* __restrict__ x, bf16* __restrict__ xb,
                        const float* __restrict__ w, bf16* __restrict__ wb)
{
    const long bid = blockIdx.x;
    const float* in;
    bf16* outp;
    long i4;
    if (bid < 16384) { in = x; outp = xb; i4 = bid * 256 + threadIdx.x; }
    else             { in = w; outp = wb; i4 = (bid - 16384) * 256 + threadIdx.x; }
    const f32x4 v = ((const f32x4*)in)[i4];
    bf16x4 o;
#pragma unroll
    for (int e = 0; e < 4; e++) o[e] = (bf16)v[e];
    ((bf16x4*)outp)[i4] = o;
}

// Batched: W[z] (1024x1024 fp32) -> Wb[z] bf16, Wtb[z] = bf16(W^T)
__global__ void prep_w3(const float* __restrict__ w0, const float* __restrict__ w1,
                        const float* __restrict__ w2, bf16* __restrict__ Wb,
                        bf16* __restrict__ Wtb)
{
    __shared__ float tile[32][33];
    const int z = blockIdx.z;
    const float* W = (z == 0) ? w0 : (z == 1) ? w1 : w2;
    const long zo = (long)z * 1024 * 1024;
    const int bx = blockIdx.x * 32, by = blockIdx.y * 32;
    const int tx = threadIdx.x & 31, ty = threadIdx.x >> 5;
#pragma unroll
    for (int i = 0; i < 32; i += 8) {
        float v = W[(long)(by + ty + i) * 1024 + bx + tx];
        tile[ty + i][tx] = v;
        Wb[zo + (long)(by + ty + i) * 1024 + bx + tx] = (bf16)v;
    }
    __syncthreads();
#pragma unroll
    for (int i = 0; i < 32; i += 8)
        Wtb[zo + (long)(bx + ty + i) * 1024 + by + tx] = (bf16)tile[tx][ty + i];
}

__global__ void prep_wout(const float* __restrict__ w, bf16* __restrict__ wh,
                          bf16* __restrict__ wl)
{
    const long i4   = (long)blockIdx.x * 256 + threadIdx.x;
    const long base = i4 * 4;
    const int  nrow = (int)(base >> 10);
    bf16x4 h, l;
    if (nrow < 1000) {
        const f32x4 v = ((const f32x4*)w)[i4];
#pragma unroll
        for (int e = 0; e < 4; e++) {
            bf16 hh = (bf16)v[e];
            h[e] = hh;
            l[e] = (bf16)(v[e] - (float)hh);
        }
    } else {
#pragma unroll
        for (int e = 0; e < 4; e++) { h[e] = (bf16)0.f; l[e] = (bf16)0.f; }
    }
    ((bf16x4*)wh)[i4] = h;
    ((bf16x4*)wl)[i4] = l;
}

__global__ __launch_bounds__(256)
void softmax_rows(const float* __restrict__ logits, float* __restrict__ out)
{
    const int row = blockIdx.x;
    const float* lp = logits + (long)row * 1024;
    const int t = threadIdx.x;
    float v[4];
    float mx = -1e30f;
#pragma unroll
    for (int i = 0; i < 4; i++) {
        const int c = t + i * 256;
        v[i] = (c < 1000) ? lp[c] : -1e30f;
        mx = fmaxf(mx, v[i]);
    }
#pragma unroll
    for (int off = 32; off; off >>= 1)
        mx = fmaxf(mx, __shfl_xor(mx, off));
    __shared__ float sm[4], ss[4];
    const int wave = t >> 6;
    if ((t & 63) == 0) sm[wave] = mx;
    __syncthreads();
    mx = fmaxf(fmaxf(sm[0], sm[1]), fmaxf(sm[2], sm[3]));
    float sum = 0.f;
#pragma unroll
    for (int i = 0; i < 4; i++) {
        v[i] = __expf(v[i] - mx);
        sum += v[i];
    }
#pragma unroll
    for (int off = 32; off; off >>= 1)
        sum += __shfl_xor(sum, off);
    if ((t & 63) == 0) ss[wave] = sum;
    __syncthreads();
    const float inv = 1.f / (ss[0] + ss[1] + ss[2] + ss[3]);
#pragma unroll
    for (int i = 0; i < 4; i++) {
        const int c = t + i * 256;
        if (c < 1000) out[(long)row * 1000 + c] = v[i] * inv;
    }
}

extern "C" void kernel_launch(void* const* d_in, const int* in_sizes, int n_in,
                              void* d_out, int out_size, void* d_ws, size_t ws_size,
                              hipStream_t stream)
{
    const float* x     = (const float*)d_in[0];
    const float* W_in  = (const float*)d_in[1];
    const float* b_in  = (const float*)d_in[2];
    const float* Ws[3] = {(const float*)d_in[3], (const float*)d_in[5], (const float*)d_in[7]};
    const float* bs[3] = {(const float*)d_in[4], (const float*)d_in[6], (const float*)d_in[8]};
    const float* W_out = (const float*)d_in[9];
    const float* b_out = (const float*)d_in[10];
    float* out = (float*)d_out;

    char* ws = (char*)d_ws;
    const size_t MB = 1u << 20;
    const long M1 = 1024L * 1024;
    // 0..32MB: xb (z0) -> {Wtbf@0, Minv@6, P@12, Bcat@18..30} -> zh/zl (L2 out)
    bf16*  xb    = (bf16*)(ws);
    bf16*  Wtbf  = (bf16*)(ws);
    bf16*  Minv  = (bf16*)(ws +  6 * MB);
    bf16*  Pmat  = (bf16*)(ws + 12 * MB);
    bf16*  Bcat  = (bf16*)(ws + 18 * MB);   // 3 x 1024x2048
    bf16*  zh    = (bf16*)(ws);             // 16 MB
    bf16*  zl    = (bf16*)(ws + 16 * MB);   // 16 MB
    bf16*  Winb  = (bf16*)(ws + 32 * MB);   //  4 MB
    bf16*  Wouth = (bf16*)(ws + 36 * MB);   //  2 MB
    bf16*  Woutl = (bf16*)(ws + 38 * MB);   //  2 MB
    bf16*  Wbf   = (bf16*)(ws + 40 * MB);   //  6 MB
    bf16*  Ccat  = (bf16*)(ws + 46 * MB);   // 12 MB (3 x 1024x2048)
    float* u     = (float*)(ws + 58 * MB);  // 32 MB (in-place) -> logits
    float* logits= (float*)(ws + 58 * MB);
    bf16*  AC_a  = (bf16*)(ws + 90 * MB);   // 32 MB
    bf16*  AC_b  = (bf16*)(ws + 122 * MB);  // 32 MB (peak 154 MB)

    const dim3 blk(256);
    const dim3 blk512(512);
    const dim3 gBig(8, 64);
    const dim3 gLay(8, 32);
    const dim3 gSm3(8, 8, 3);
    const dim3 gT3(32, 32, 3);

    // 1-2: conversions
    conv_xw<<<18432, blk, 0, stream>>>(x, xb, W_in, Winb);
    prep_wout<<<1024, blk, 0, stream>>>(W_out, Wouth, Woutl);

    // 3: z0 = x@W_in^T + b_in; u=z0 (fp32), AC_a=[11relu(z0) | z0+0.1*b1]
    gemm_bt<0><<<gBig, blk, 0, stream>>>(xb, Winb, u, AC_a, AC_a + 1024,
                                         nullptr, b_in, bs[0],
                                         8192, 1024, 2048, 2048, 2048,
                                         1024, 2048, 2048, 1.f, 0, 0, 0, 0);

    // 4: weight transposes (xb region is dead now)
    prep_w3<<<gT3, blk, 0, stream>>>(Ws[0], Ws[1], Ws[2], Wbf, Wtbf);
    // 5: Minv[z] -> Minv (ld1024) and Bcat[:, :1024] (ld2048)
    gemm_bt<1><<<gSm3, blk, 0, stream>>>(Wtbf, Wtbf, nullptr, Minv, Bcat,
                                         nullptr, nullptr, nullptr,
                                         1024, 1024, 1024, 1024, 1024,
                                         0, 1024, 2048, 1.f, M1, M1, M1, 2 * M1);
    // 6: Bcat[:, 1024:] = 0.1 * Minv @ W^T
    gemm_bt<2><<<gSm3, blk, 0, stream>>>(Minv, Wbf, nullptr, Bcat + 1024, nullptr,
                                         nullptr, nullptr, nullptr,
                                         1024, 1024, 1024, 1024, 1024,
                                         0, 2048, 0, C_DT, M1, M1, 2 * M1, 0);
    // 7: P = W @ Minv (Minv symmetric); also Ccat[:, :1024] = 0.1*P
    gemm_bt<2><<<gSm3, blk, 0, stream>>>(Wbf, Minv, nullptr, Pmat, Ccat,
                                         nullptr, nullptr, nullptr,
                                         1024, 1024, 1024, 1024, 1024,
                                         0, 1024, 2048, 1.f, M1, M1, M1, 2 * M1);
    // 8: Ccat[:, 1024:] = 0.01 * P @ W^T
    gemm_bt<2><<<gSm3, blk, 0, stream>>>(Pmat, Wbf, nullptr, Ccat + 1024, nullptr,
                                         nullptr, nullptr, nullptr,
                                         1024, 1024, 1024, 1024, 1024,
                                         0, 2048, 0, 0.01f, M1, M1, 2 * M1, 0);

    // 9-10: fused layers 0,1 (V in registers only; 8-phase schedule)
    gemm_layer8<<<gLay, blk512, 0, stream>>>(AC_a, Bcat, Ccat, u, AC_b, bs[0], bs[1]);
    gemm_layer8<<<gLay, blk512, 0, stream>>>(AC_b, Bcat + 2 * M1, Ccat + 2 * M1,
                                             u, AC_a, bs[1], bs[2]);
    // 11: layer 2 u-only: z = AC_a @ Ccat2^T - u - 0.1*b3 -> zh/zl
    gemm_bt<5><<<gBig, blk, 0, stream>>>(AC_a, Ccat + 4 * M1, nullptr, zh, zl,
                                         u, bs[2], nullptr,
                                         8192, 1024, 2048, 2048, 2048,
                                         1024, 1024, 1024, 1.f, 0, 0, 0, 0);

    // 12-13: logits (3-term split) + softmax
    gemm_split<<<gBig, blk, 0, stream>>>(zh, zl, Wouth, Woutl, logits, b_out,
                                         8192, 1024, 1024, 1000);
    softmax_rows<<<8192, blk, 0, stream>>>(logits, out);
}

// Round 2
// 512.707 us; speedup vs baseline: 1.0519x; 1.0519x over previous
//
#include <hip/hip_runtime.h>
#include <hip/hip_bf16.h>
#include <cstdint>

// I/O is FP32. Derivation: c=DT=0.1, d=1+DT/EPS=11; layer out = (-u,-v):
//   V = [vr | rhsu] @ Bcat^T, Bcat = [Minv | 0.1*(Minv W^T)] (1024x2048),
//   u_raw = 0.1 V W^T = AC @ Ccat^T, Ccat = 0.1*W@Bcat = [0.1*P | 0.01*P@W^T],
//   P = W@Minv;  un = u_raw - u_in - 0.1 b;  AC_next = [10relu(un)-V | un+0.1b'],
//   Minv = (I - (0.01/11) W^T W)/11  (Neumann, trunc err ~1.5e-6).
// R8: gemm_layer8 schedule fix after R7 neutral result:
//   (a) bijective XCD remap for (8,32) grid: XCD owns by-quad x all bx ->
//       per-K-tile XCD working set ~384KB (was 4MB streaming = L2 thrash,
//       FETCH 151MB). A loads become L2 hits.
//   (b) all 8 next-tile DMA issued in phases 1-2 (issue order = consumption
//       order) -> every load gets >=3 phases (~2000cyc) slack vs the 1-2
//       phases R7 gave the late chunks. vmcnt(2)@ph1, vmcnt(4)@ph2 only.
//   (c) redundant leading barriers of ph3/ph4 removed (6 barriers/tile).

typedef __bf16 bf16;
typedef __bf16 bf16x4 __attribute__((ext_vector_type(4)));
typedef __bf16 bf16x8 __attribute__((ext_vector_type(8)));
typedef float  f32x4  __attribute__((ext_vector_type(4)));

#define C_DT    0.1f
#define C_DTEPS 10.0f
#define C_DINV  (1.0f/11.0f)
#define C_MSC   (0.01f/121.0f)

__device__ __forceinline__ void async_load16(const bf16* g, bf16* l) {
    __builtin_amdgcn_global_load_lds(
        (__attribute__((address_space(1))) void*)(g),
        (__attribute__((address_space(3))) void*)(l),
        16, 0, 0);
}

// XCD-aware remap for (8,64) grids: per-XCD L2 working set ~ row-panel + B.
__device__ __forceinline__ void remap_block(int& bx, int& by) {
    if (gridDim.y == 64) {
        const int lin  = by * 8 + bx;
        const int xcd  = lin & 7;
        const int slot = lin >> 3;
        by = xcd * 8 + (slot & 7);
        bx = slot >> 3;
    }
}

// (8,32) grid: XCD owns 4 consecutive by (4MB A panel) x all 8 bx.
// Per-K-tile XCD working set: 4x256x64x2B (A) + 8x2x128x64x2B (B) ~ 384KB.
__device__ __forceinline__ void remap_block32(int& bx, int& by) {
    const int lin  = by * 8 + bx;
    const int xcd  = lin & 7;
    const int slot = lin >> 3;      // 0..31
    by = xcd * 4 + (slot & 3);
    bx = slot >> 2;
}

// ---------------------------------------------------------------------------
// C = A @ B^T (A: MxK ld lda, B: NxK ld ldb, bf16). 128x128 tile, BK=32,
// double-buffered, batched over blockIdx.z.
// EPI 0 Z0   : t=a+e1[n]; out_f=t; out_b1=11*relu(t); out_b2=t+0.1*e2[n]
// EPI 1 MINV : v=(m==n?1/11:0)-C_MSC*a; out_b1=v; out_b2=v
// EPI 2 SCALE: out_b1 = sgn*a; if(out_b2) out_b2 = 0.1*sgn*a
// EPI 5 ULAST: un=sgn*a-e0[m*ldf+n]-0.1*e1[n]; out_b1=hi(un); out_b2=lo(un)
// ---------------------------------------------------------------------------
template<int EPI>
__global__ __launch_bounds__(256, 2)
void gemm_bt(const bf16* __restrict__ A, const bf16* __restrict__ B,
             float* __restrict__ out_f,
             bf16* __restrict__ out_b1, bf16* __restrict__ out_b2,
             const float* __restrict__ e0, const float* __restrict__ e1,
             const float* __restrict__ e2,
             int M, int N, int K, int lda, int ldb,
             int ldf, int ld1, int ld2, float sgn,
             long zsA, long zsB, long zs1, long zs2)
{
    __shared__ __attribute__((aligned(16))) char smem[32768];
    bf16* sAe = (bf16*)smem;             // 2 x 4096 elements
    bf16* sBe = (bf16*)(smem + 16384);

    const int t    = threadIdx.x;
    const int wave = t >> 6;
    const int lane = t & 63;
    int bx = blockIdx.x, by = blockIdx.y;
    remap_block(bx, by);
    const long zb = blockIdx.z;
    A += zb * zsA;
    B += zb * zsB;
    if (out_b1) out_b1 += zb * zs1;
    if (out_b2) out_b2 += zb * zs2;

    const long row0 = (long)by * 128;
    const long col0 = (long)bx * 128;
    const int wr = wave >> 1, wc = wave & 1;

    f32x4 acc[4][4];
#pragma unroll
    for (int i = 0; i < 4; i++)
#pragma unroll
        for (int j = 0; j < 4; j++)
            acc[i][j] = f32x4{0.f, 0.f, 0.f, 0.f};

    const int  q  = t >> 2;
    const int  gp = ((t & 3) + 4 - ((q + (q >> 2)) & 3)) & 3;
    const bf16* gA = A + (row0 + q) * (long)lda + gp * 8;
    const bf16* gB = B + (col0 + q) * (long)ldb + gp * 8;

    const int l15  = lane & 15;
    const int fch  = ((lane >> 4) + l15 + (l15 >> 2)) & 3;
    const int aoff = (wr * 64 + l15) * 32 + fch * 8;
    const int boff = (wc * 64 + l15) * 32 + fch * 8;

    auto stage = [&](int buf, int k0) {
        bf16* dA = sAe + buf * 4096 + wave * 512;
        bf16* dB = sBe + buf * 4096 + wave * 512;
        async_load16(gA + k0,                     dA);
        async_load16(gA + 64 * (long)lda + k0,    dA + 2048);
        async_load16(gB + k0,                     dB);
        async_load16(gB + 64 * (long)ldb + k0,    dB + 2048);
    };

    const int nIter = K >> 5;
    stage(0, 0);
    __syncthreads();
    for (int k = 0; k < nIter; k++) {
        const int cur = k & 1;
        if (k + 1 < nIter) stage(cur ^ 1, (k + 1) << 5);

        bf16x8 af[4], bfv[4];
#pragma unroll
        for (int i = 0; i < 4; i++)
            af[i] = *(const bf16x8*)(sAe + cur * 4096 + aoff + i * 16 * 32);
#pragma unroll
        for (int j = 0; j < 4; j++)
            bfv[j] = *(const bf16x8*)(sBe + cur * 4096 + boff + j * 16 * 32);
#pragma unroll
        for (int i = 0; i < 4; i++)
#pragma unroll
            for (int j = 0; j < 4; j++)
                acc[i][j] = __builtin_amdgcn_mfma_f32_16x16x32_bf16(
                    af[i], bfv[j], acc[i][j], 0, 0, 0);

        __syncthreads();
    }

    float* epi = (float*)smem + wave * 1024;
    const int wbase = (lane >> 4) * 256 + (l15 >> 2) * 4 + (l15 & 3);

#pragma unroll
    for (int i = 0; i < 4; i++) {
#pragma unroll
        for (int j = 0; j < 4; j++)
#pragma unroll
            for (int r = 0; r < 4; r++)
                epi[wbase + r * 64 + 16 * j] = acc[i][j][r];

#pragma unroll
        for (int qq = 0; qq < 4; qq++) {
            const f32x4 a4 = ((const f32x4*)epi)[qq * 64 + lane];
            const long m = row0 + wr * 64 + i * 16 + qq * 4 + (lane >> 4);
            const long n = col0 + wc * 64 + 4 * l15;

            if (EPI == 0) {
                const f32x4 b1 = *(const f32x4*)(e1 + n);
                const f32x4 b2 = *(const f32x4*)(e2 + n);
                f32x4 tv; bf16x4 rv, hv;
#pragma unroll
                for (int e = 0; e < 4; e++) {
                    tv[e] = a4[e] + b1[e];
                    rv[e] = (bf16)(11.f * fmaxf(tv[e], 0.f));
                    hv[e] = (bf16)(tv[e] + C_DT * b2[e]);
                }
                *(f32x4*)(out_f + m * (long)ldf + n)    = tv;
                *(bf16x4*)(out_b1 + m * (long)ld1 + n)  = rv;
                *(bf16x4*)(out_b2 + m * (long)ld2 + n)  = hv;
            } else if (EPI == 1) {
                bf16x4 ov;
#pragma unroll
                for (int e = 0; e < 4; e++)
                    ov[e] = (bf16)(((m == n + e) ? C_DINV : 0.f) - C_MSC * a4[e]);
                *(bf16x4*)(out_b1 + m * (long)ld1 + n) = ov;
                *(bf16x4*)(out_b2 + m * (long)ld2 + n) = ov;
            } else if (EPI == 2) {
                bf16x4 ov, o2;
#pragma unroll
                for (int e = 0; e < 4; e++) {
                    ov[e] = (bf16)(sgn * a4[e]);
                    o2[e] = (bf16)(C_DT * sgn * a4[e]);
                }
                *(bf16x4*)(out_b1 + m * (long)ld1 + n) = ov;
                if (out_b2) *(bf16x4*)(out_b2 + m * (long)ld2 + n) = o2;
            } else {  // EPI 5
                const f32x4 u0 = *(const f32x4*)(e0 + m * (long)ldf + n);
                const f32x4 b1 = *(const f32x4*)(e1 + n);
                bf16x4 hv, lv;
#pragma unroll
                for (int e = 0; e < 4; e++) {
                    float un = sgn * a4[e] - u0[e] - C_DT * b1[e];
                    bf16 h = (bf16)un;
                    hv[e] = h;
                    lv[e] = (bf16)(un - (float)h);
                }
                *(bf16x4*)(out_b1 + m * (long)ld1 + n) = hv;
                *(bf16x4*)(out_b2 + m * (long)ld2 + n) = lv;
            }
        }
    }
}

// ---------------------------------------------------------------------------
// Fused layer, 4-phase counted-vmcnt schedule (R8).
// accV = AC@Bcat^T, accU = AC@Ccat^T (K=2048) in one block.
// BM=256 BN=128 BK=64; 8 waves (2Mx4N), per-wave 128x32 per accumulator.
// LDS layout (bf16 elems): A[2][4 chunks][64x64] @0, B1[2][2][64x64] @32768,
// B2[2][2][64x64] @49152. Chunk = 64 rows x 64 cols, 16B-slot XOR swizzle
// (slot ^= row&7) realized via inverse-swizzled global source (linear
// global_load_lds dest) + matching XOR on ds_read addresses.
// Per K-tile: 4 phases (row-half rh x k-half kh), 16 MFMA each.
// All 8 next-tile loads issued in ph1 (A0,A2,B1_0,B1_1) + ph2 (B2_0,B2_1,
// A1,A3); issue order = consumption order, giving every load >=3 phases of
// slack. Waits: vmcnt(2)@ph1 (oldest 6 = ph1-needed set), vmcnt(4)@ph2
// (A1,A3 done), none at ph3/ph4; last tile drains. 6 barriers/tile.
// Epilogue: un = accU - u - 0.1*bl;  u <- un (in-place);
//           ACo[:, :1024] = 10*relu(un) - accV;  ACo[:, 1024:] = un + 0.1*bn.
// ---------------------------------------------------------------------------
__global__ __launch_bounds__(512, 2)
void gemm_layer8(const bf16* __restrict__ A, const bf16* __restrict__ B1,
                 const bf16* __restrict__ B2, float* __restrict__ u,
                 bf16* __restrict__ ACo,
                 const float* __restrict__ bl, const float* __restrict__ bn)
{
    __shared__ __attribute__((aligned(16))) bf16 sm[65536];   // 128 KiB

    const int t    = threadIdx.x;
    const int wave = t >> 6;
    const int lane = t & 63;
    const int l15  = lane & 15;
    const int lq   = lane >> 4;
    int bx = blockIdx.x, by = blockIdx.y;
    remap_block32(bx, by);
    const long row0 = (long)by * 256;
    const long col0 = (long)bx * 128;
    const int wr = wave >> 2;          // 0..1 (M half)
    const int wc = wave & 3;           // 0..3 (N quarter)

    f32x4 accV[8][2], accU[8][2];
#pragma unroll
    for (int i = 0; i < 8; i++)
#pragma unroll
        for (int j = 0; j < 2; j++) {
            accV[i][j] = f32x4{0.f, 0.f, 0.f, 0.f};
            accU[i][j] = f32x4{0.f, 0.f, 0.f, 0.f};
        }

    // staging: thread t covers chunk byte [t*16, t*16+16) (linear LDS dest);
    // row r = t>>3, phys slot s = t&7 holds logical slot s^(r&7) -> fetch
    // global col-group sg = (t&7)^((t>>3)&7).
    const int tr = t >> 3;
    const int sg = (t & 7) ^ (tr & 7);
    const bf16* gA  = A  + (row0 + tr) * 2048 + sg * 8;
    const bf16* gB1 = B1 + (col0 + tr) * 2048 + sg * 8;
    const bf16* gB2 = B2 + (col0 + tr) * 2048 + sg * 8;
    bf16* const ldA  = sm + wave * 512;          // + buf*16384 + ci*4096
    bf16* const ldB1 = sm + 32768 + wave * 512;  // + buf*8192  + cb*4096
    bf16* const ldB2 = sm + 49152 + wave * 512;

    auto stA = [&](int buf, int ci, int k0) {
        async_load16(gA + (long)ci * 131072 + k0, ldA + buf * 16384 + ci * 4096);
    };
    auto stB1v = [&](int buf, int cb, int k0) {
        async_load16(gB1 + (long)cb * 131072 + k0, ldB1 + buf * 8192 + cb * 4096);
    };
    auto stB2v = [&](int buf, int cb, int k0) {
        async_load16(gB2 + (long)cb * 131072 + k0, ldB2 + buf * 8192 + cb * 4096);
    };

    // read addressing: logical (row rr, k-group q=kh*4+lq) -> phys slot q^(rr&7)
    const int sl0 = lq ^ (l15 & 7);          // kh=0
    const int sl1 = (4 + lq) ^ (l15 & 7);    // kh=1
    const int aro = l15 * 64;                // + ci*4096 + fi*1024 + sl*8
    const int cbo = (wc >> 1) * 4096;
    const int bro = ((wc & 1) * 32 + l15) * 64;

    // prologue: tile 0, issue order = consumption order
    stA(0, 0, 0); stA(0, 2, 0);
    stB1v(0, 0, 0); stB1v(0, 1, 0);
    stB2v(0, 0, 0); stB2v(0, 1, 0);
    stA(0, 1, 0); stA(0, 3, 0);

    for (int kt = 0; kt < 32; ++kt) {
        const int  cur = kt & 1, nb = cur ^ 1;
        const bool st  = kt < 31;
        const int  k0n = (kt + 1) << 6;
        const bf16* bA  = sm + cur * 16384;
        const bf16* bB1 = sm + 32768 + cur * 8192;
        const bf16* bB2 = sm + 49152 + cur * 8192;
        bf16x8 a[4], b1k[2], b2k[2];

        // ---- phase 1: rh=0, kh=0 ----
        asm volatile("s_waitcnt vmcnt(2)" ::: "memory");
        __builtin_amdgcn_s_barrier();
#pragma unroll
        for (int fi = 0; fi < 4; ++fi)
            a[fi] = *(const bf16x8*)(bA + wr * 8192 + fi * 1024 + aro + sl0 * 8);
#pragma unroll
        for (int fj = 0; fj < 2; ++fj) {
            b1k[fj] = *(const bf16x8*)(bB1 + cbo + fj * 1024 + bro + sl0 * 8);
            b2k[fj] = *(const bf16x8*)(bB2 + cbo + fj * 1024 + bro + sl0 * 8);
        }
        if (st) { stA(nb, 0, k0n); stA(nb, 2, k0n); stB1v(nb, 0, k0n); stB1v(nb, 1, k0n); }
        __builtin_amdgcn_s_barrier();
        asm volatile("s_waitcnt lgkmcnt(0)" ::: "memory");
        __builtin_amdgcn_s_setprio(1);
#pragma unroll
        for (int fi = 0; fi < 4; ++fi)
#pragma unroll
            for (int fj = 0; fj < 2; ++fj) {
                accV[fi][fj] = __builtin_amdgcn_mfma_f32_16x16x32_bf16(
                    a[fi], b1k[fj], accV[fi][fj], 0, 0, 0);
                accU[fi][fj] = __builtin_amdgcn_mfma_f32_16x16x32_bf16(
                    a[fi], b2k[fj], accU[fi][fj], 0, 0, 0);
            }
        __builtin_amdgcn_s_setprio(0);

        // ---- phase 2: rh=1, kh=0 (needs A1,A3 of this tile) ----
        if (st) asm volatile("s_waitcnt vmcnt(4)" ::: "memory");
        else    asm volatile("s_waitcnt vmcnt(0)" ::: "memory");
        __builtin_amdgcn_s_barrier();
#pragma unroll
        for (int fi = 0; fi < 4; ++fi)
            a[fi] = *(const bf16x8*)(bA + wr * 8192 + 4096 + fi * 1024 + aro + sl0 * 8);
        if (st) { stB2v(nb, 0, k0n); stB2v(nb, 1, k0n); stA(nb, 1, k0n); stA(nb, 3, k0n); }
        __builtin_amdgcn_s_barrier();
        asm volatile("s_waitcnt lgkmcnt(0)" ::: "memory");
        __builtin_amdgcn_s_setprio(1);
#pragma unroll
        for (int fi = 0; fi < 4; ++fi)
#pragma unroll
            for (int fj = 0; fj < 2; ++fj) {
                accV[4 + fi][fj] = __builtin_amdgcn_mfma_f32_16x16x32_bf16(
                    a[fi], b1k[fj], accV[4 + fi][fj], 0, 0, 0);
                accU[4 + fi][fj] = __builtin_amdgcn_mfma_f32_16x16x32_bf16(
                    a[fi], b2k[fj], accU[4 + fi][fj], 0, 0, 0);
            }
        __builtin_amdgcn_s_setprio(0);

        // ---- phase 3: rh=0, kh=1 (data resident; no leading barrier) ----
#pragma unroll
        for (int fi = 0; fi < 4; ++fi)
            a[fi] = *(const bf16x8*)(bA + wr * 8192 + fi * 1024 + aro + sl1 * 8);
#pragma unroll
        for (int fj = 0; fj < 2; ++fj) {
            b1k[fj] = *(const bf16x8*)(bB1 + cbo + fj * 1024 + bro + sl1 * 8);
            b2k[fj] = *(const bf16x8*)(bB2 + cbo + fj * 1024 + bro + sl1 * 8);
        }
        __builtin_amdgcn_s_barrier();
        asm volatile("s_waitcnt lgkmcnt(0)" ::: "memory");
        __builtin_amdgcn_s_setprio(1);
#pragma unroll
        for (int fi = 0; fi < 4; ++fi)
#pragma unroll
            for (int fj = 0; fj < 2; ++fj) {
                accV[fi][fj] = __builtin_amdgcn_mfma_f32_16x16x32_bf16(
                    a[fi], b1k[fj], accV[fi][fj], 0, 0, 0);
                accU[fi][fj] = __builtin_amdgcn_mfma_f32_16x16x32_bf16(
                    a[fi], b2k[fj], accU[fi][fj], 0, 0, 0);
            }
        __builtin_amdgcn_s_setprio(0);

        // ---- phase 4: rh=1, kh=1 ----
#pragma unroll
        for (int fi = 0; fi < 4; ++fi)
            a[fi] = *(const bf16x8*)(bA + wr * 8192 + 4096 + fi * 1024 + aro + sl1 * 8);
        __builtin_amdgcn_s_barrier();
        asm volatile("s_waitcnt lgkmcnt(0)" ::: "memory");
        __builtin_amdgcn_s_setprio(1);
#pragma unroll
        for (int fi = 0; fi < 4; ++fi)
#pragma unroll
            for (int fj = 0; fj < 2; ++fj) {
                accV[4 + fi][fj] = __builtin_amdgcn_mfma_f32_16x16x32_bf16(
                    a[fi], b1k[fj], accV[4 + fi][fj], 0, 0, 0);
                accU[4 + fi][fj] = __builtin_amdgcn_mfma_f32_16x16x32_bf16(
                    a[fi], b2k[fj], accU[4 + fi][fj], 0, 0, 0);
            }
        __builtin_amdgcn_s_setprio(0);
    }

    // Epilogue: per-wave private 1024-float scratch at sm[0..32KB) (= buf0 A
    // region; tile 31 read buf1 only, all ds_reads drained by per-phase lgkm).
    // Handles two row-frags (32x32 block) per round; V then U through the
    // same region (same-wave DS ops are in-order).
    float* epi = (float*)sm + wave * 1024;
    const int ew = lq * 128 + l15;     // row=(lq*4+r), col=l15: idx = (lq*4)*32 + l15

#pragma unroll
    for (int fib = 0; fib < 4; ++fib) {
#pragma unroll
        for (int f2 = 0; f2 < 2; ++f2)
#pragma unroll
            for (int fj = 0; fj < 2; ++fj)
#pragma unroll
                for (int r = 0; r < 4; ++r)
                    epi[f2 * 512 + ew + r * 32 + fj * 16] = accV[fib * 2 + f2][fj][r];
        f32x4 v4[4];
#pragma unroll
        for (int qq = 0; qq < 4; ++qq)
            v4[qq] = ((const f32x4*)epi)[qq * 64 + lane];
#pragma unroll
        for (int f2 = 0; f2 < 2; ++f2)
#pragma unroll
            for (int fj = 0; fj < 2; ++fj)
#pragma unroll
                for (int r = 0; r < 4; ++r)
                    epi[f2 * 512 + ew + r * 32 + fj * 16] = accU[fib * 2 + f2][fj][r];

#pragma unroll
        for (int qq = 0; qq < 4; ++qq) {
            const f32x4 a4 = ((const f32x4*)epi)[qq * 64 + lane];
            const long m = row0 + wr * 128 + fib * 32 + qq * 8 + (lane >> 3);
            const long n = col0 + wc * 32 + (lane & 7) * 4;
            const long iu = m * 1024 + n;
            const f32x4 u0 = *(const f32x4*)(u + iu);
            const f32x4 c1 = *(const f32x4*)(bl + n);
            const f32x4 c2 = *(const f32x4*)(bn + n);
            f32x4 un; bf16x4 rv, hv;
#pragma unroll
            for (int e = 0; e < 4; ++e) {
                un[e] = a4[e] - u0[e] - C_DT * c1[e];
                rv[e] = (bf16)(C_DTEPS * fmaxf(un[e], 0.f) - v4[qq][e]);
                hv[e] = (bf16)(un[e] + C_DT * c2[e]);
            }
            *(f32x4*)(u + iu) = un;
            *(bf16x4*)(ACo + m * 2048 + n)        = rv;
            *(bf16x4*)(ACo + m * 2048 + 1024 + n) = hv;
        }
    }
}

// logits = (Ah+Al)@(Bh+Bl)^T + bias (3-term), fp32 out, double-buffered.
__global__ __launch_bounds__(256, 2)
void gemm_split(const bf16* __restrict__ Ah, const bf16* __restrict__ Al,
                const bf16* __restrict__ Bh, const bf16* __restrict__ Bl,
                float* __restrict__ out, const float* __restrict__ bias,
                int M, int N, int K, int blim)
{
    __shared__ __attribute__((aligned(16))) char smem[65536];
    bf16* sAh = (bf16*)smem;
    bf16* sAl = (bf16*)(smem + 16384);
    bf16* sBh = (bf16*)(smem + 32768);
    bf16* sBl = (bf16*)(smem + 49152);

    const int t    = threadIdx.x;
    const int wave = t >> 6;
    const int lane = t & 63;
    int bx = blockIdx.x, by = blockIdx.y;
    remap_block(bx, by);
    const long row0 = (long)by * 128;
    const long col0 = (long)bx * 128;
    const int wr = wave >> 1, wc = wave & 1;

    f32x4 acc[4][4];
#pragma unroll
    for (int i = 0; i < 4; i++)
#pragma unroll
        for (int j = 0; j < 4; j++)
            acc[i][j] = f32x4{0.f, 0.f, 0.f, 0.f};

    const int  q  = t >> 2;
    const int  gp = ((t & 3) + 4 - ((q + (q >> 2)) & 3)) & 3;
    const long gao = (row0 + q) * (long)K + gp * 8;
    const long gbo = (col0 + q) * (long)K + gp * 8;

    const int l15  = lane & 15;
    const int fch  = ((lane >> 4) + l15 + (l15 >> 2)) & 3;
    const int aoff = (wr * 64 + l15) * 32 + fch * 8;
    const int boff = (wc * 64 + l15) * 32 + fch * 8;

    auto stage = [&](int buf, int k0) {
        const int d = buf * 4096 + wave * 512;
        async_load16(Ah + gao + k0,                 sAh + d);
        async_load16(Ah + gao + 64 * (long)K + k0,  sAh + d + 2048);
        async_load16(Al + gao + k0,                 sAl + d);
        async_load16(Al + gao + 64 * (long)K + k0,  sAl + d + 2048);
        async_load16(Bh + gbo + k0,                 sBh + d);
        async_load16(Bh + gbo + 64 * (long)K + k0,  sBh + d + 2048);
        async_load16(Bl + gbo + k0,                 sBl + d);
        async_load16(Bl + gbo + 64 * (long)K + k0,  sBl + d + 2048);
    };

    const int nIter = K >> 5;
    stage(0, 0);
    __syncthreads();
    for (int k = 0; k < nIter; k++) {
        const int cur = k & 1;
        if (k + 1 < nIter) stage(cur ^ 1, (k + 1) << 5);

        bf16x8 ah[4], al[4], bh[4], bl[4];
#pragma unroll
        for (int i = 0; i < 4; i++) {
            ah[i] = *(const bf16x8*)(sAh + cur * 4096 + aoff + i * 16 * 32);
            al[i] = *(const bf16x8*)(sAl + cur * 4096 + aoff + i * 16 * 32);
        }
#pragma unroll
        for (int j = 0; j < 4; j++) {
            bh[j] = *(const bf16x8*)(sBh + cur * 4096 + boff + j * 16 * 32);
            bl[j] = *(const bf16x8*)(sBl + cur * 4096 + boff + j * 16 * 32);
        }
#pragma unroll
        for (int i = 0; i < 4; i++)
#pragma unroll
            for (int j = 0; j < 4; j++) {
                acc[i][j] = __builtin_amdgcn_mfma_f32_16x16x32_bf16(
                    ah[i], bh[j], acc[i][j], 0, 0, 0);
                acc[i][j] = __builtin_amdgcn_mfma_f32_16x16x32_bf16(
                    ah[i], bl[j], acc[i][j], 0, 0, 0);
                acc[i][j] = __builtin_amdgcn_mfma_f32_16x16x32_bf16(
                    al[i], bh[j], acc[i][j], 0, 0, 0);
            }
        __syncthreads();
    }

    float* epi = (float*)smem + wave * 1024;
    const int wbase = (lane >> 4) * 256 + (l15 >> 2) * 4 + (l15 & 3);

#pragma unroll
    for (int i = 0; i < 4; i++) {
#pragma unroll
        for (int j = 0; j < 4; j++)
#pragma unroll
            for (int r = 0; r < 4; r++)
                epi[wbase + r * 64 + 16 * j] = acc[i][j][r];

#pragma unroll
        for (int qq = 0; qq < 4; qq++) {
            f32x4 a4 = ((const f32x4*)epi)[qq * 64 + lane];
            const long m = row0 + wr * 64 + i * 16 + qq * 4 + (lane >> 4);
            const long n = col0 + wc * 64 + 4 * l15;
            f32x4 bv = f32x4{0.f, 0.f, 0.f, 0.f};
            if (n < blim) bv = *(const f32x4*)(bias + n);
#pragma unroll
            for (int e = 0; e < 4; e++) a4[e] += bv[e];
            *(f32x4*)(out + m * (long)N + n) = a4;
        }
    }
}

// fp32 -> bf16 for x (16384 blocks) and W_in (2048 blocks) in one dispatch
__global__ void conv_xw(const float* __restrict__ x, bf16* __restrict__ xb,
                        const float* __restrict__ w, bf16* __restrict__ wb)
{
    const long bid = blockIdx.x;
    const float* in;
    bf16* outp;
    long i4;
    if (bid < 16384) { in = x; outp = xb; i4 = bid * 256 + threadIdx.x; }
    else             { in = w; outp = wb; i4 = (bid - 16384) * 256 + threadIdx.x; }
    const f32x4 v = ((const f32x4*)in)[i4];
    bf16x4 o;
#pragma unroll
    for (int e = 0; e < 4; e++) o[e] = (bf16)v[e];
    ((bf16x4*)outp)[i4] = o;
}

// Batched: W[z] (1024x1024 fp32) -> Wb[z] bf16, Wtb[z] = bf16(W^T)
__global__ void prep_w3(const float* __restrict__ w0, const float* __restrict__ w1,
                        const float* __restrict__ w2, bf16* __restrict__ Wb,
                        bf16* __restrict__ Wtb)
{
    __shared__ float tile[32][33];
    const int z = blockIdx.z;
    const float* W = (z == 0) ? w0 : (z == 1) ? w1 : w2;
    const long zo = (long)z * 1024 * 1024;
    const int bx = blockIdx.x * 32, by = blockIdx.y * 32;
    const int tx = threadIdx.x & 31, ty = threadIdx.x >> 5;
#pragma unroll
    for (int i = 0; i < 32; i += 8) {
        float v = W[(long)(by + ty + i) * 1024 + bx + tx];
        tile[ty + i][tx] = v;
        Wb[zo + (long)(by + ty + i) * 1024 + bx + tx] = (bf16)v;
    }
    __syncthreads();
#pragma unroll
    for (int i = 0; i < 32; i += 8)
        Wtb[zo + (long)(bx + ty + i) * 1024 + by + tx] = (bf16)tile[tx][ty + i];
}

__global__ void prep_wout(const float* __restrict__ w, bf16* __restrict__ wh,
                          bf16* __restrict__ wl)
{
    const long i4   = (long)blockIdx.x * 256 + threadIdx.x;
    const long base = i4 * 4;
    const int  nrow = (int)(base >> 10);
    bf16x4 h, l;
    if (nrow < 1000) {
        const f32x4 v = ((const f32x4*)w)[i4];
#pragma unroll
        for (int e = 0; e < 4; e++) {
            bf16 hh = (bf16)v[e];
            h[e] = hh;
            l[e] = (bf16)(v[e] - (float)hh);
        }
    } else {
#pragma unroll
        for (int e = 0; e < 4; e++) { h[e] = (bf16)0.f; l[e] = (bf16)0.f; }
    }
    ((bf16x4*)wh)[i4] = h;
    ((bf16x4*)wl)[i4] = l;
}

__global__ __launch_bounds__(256)
void softmax_rows(const float* __restrict__ logits, float* __restrict__ out)
{
    const int row = blockIdx.x;
    const float* lp = logits + (long)row * 1024;
    const int t = threadIdx.x;
    float v[4];
    float mx = -1e30f;
#pragma unroll
    for (int i = 0; i < 4; i++) {
        const int c = t + i * 256;
        v[i] = (c < 1000) ? lp[c] : -1e30f;
        mx = fmaxf(mx, v[i]);
    }
#pragma unroll
    for (int off = 32; off; off >>= 1)
        mx = fmaxf(mx, __shfl_xor(mx, off));
    __shared__ float sm[4], ss[4];
    const int wave = t >> 6;
    if ((t & 63) == 0) sm[wave] = mx;
    __syncthreads();
    mx = fmaxf(fmaxf(sm[0], sm[1]), fmaxf(sm[2], sm[3]));
    float sum = 0.f;
#pragma unroll
    for (int i = 0; i < 4; i++) {
        v[i] = __expf(v[i] - mx);
        sum += v[i];
    }
#pragma unroll
    for (int off = 32; off; off >>= 1)
        sum += __shfl_xor(sum, off);
    if ((t & 63) == 0) ss[wave] = sum;
    __syncthreads();
    const float inv = 1.f / (ss[0] + ss[1] + ss[2] + ss[3]);
#pragma unroll
    for (int i = 0; i < 4; i++) {
        const int c = t + i * 256;
        if (c < 1000) out[(long)row * 1000 + c] = v[i] * inv;
    }
}

extern "C" void kernel_launch(void* const* d_in, const int* in_sizes, int n_in,
                              void* d_out, int out_size, void* d_ws, size_t ws_size,
                              hipStream_t stream)
{
    const float* x     = (const float*)d_in[0];
    const float* W_in  = (const float*)d_in[1];
    const float* b_in  = (const float*)d_in[2];
    const float* Ws[3] = {(const float*)d_in[3], (const float*)d_in[5], (const float*)d_in[7]};
    const float* bs[3] = {(const float*)d_in[4], (const float*)d_in[6], (const float*)d_in[8]};
    const float* W_out = (const float*)d_in[9];
    const float* b_out = (const float*)d_in[10];
    float* out = (float*)d_out;

    char* ws = (char*)d_ws;
    const size_t MB = 1u << 20;
    const long M1 = 1024L * 1024;
    // 0..32MB: xb (z0) -> {Wtbf@0, Minv@6, P@12, Bcat@18..30} -> zh/zl (L2 out)
    bf16*  xb    = (bf16*)(ws);
    bf16*  Wtbf  = (bf16*)(ws);
    bf16*  Minv  = (bf16*)(ws +  6 * MB);
    bf16*  Pmat  = (bf16*)(ws + 12 * MB);
    bf16*  Bcat  = (bf16*)(ws + 18 * MB);   // 3 x 1024x2048
    bf16*  zh    = (bf16*)(ws);             // 16 MB
    bf16*  zl    = (bf16*)(ws + 16 * MB);   // 16 MB
    bf16*  Winb  = (bf16*)(ws + 32 * MB);   //  4 MB
    bf16*  Wouth = (bf16*)(ws + 36 * MB);   //  2 MB
    bf16*  Woutl = (bf16*)(ws + 38 * MB);   //  2 MB
    bf16*  Wbf   = (bf16*)(ws + 40 * MB);   //  6 MB
    bf16*  Ccat  = (bf16*)(ws + 46 * MB);   // 12 MB (3 x 1024x2048)
    float* u     = (float*)(ws + 58 * MB);  // 32 MB (in-place) -> logits
    float* logits= (float*)(ws + 58 * MB);
    bf16*  AC_a  = (bf16*)(ws + 90 * MB);   // 32 MB
    bf16*  AC_b  = (bf16*)(ws + 122 * MB);  // 32 MB (peak 154 MB)

    const dim3 blk(256);
    const dim3 blk512(512);
    const dim3 gBig(8, 64);
    const dim3 gLay(8, 32);
    const dim3 gSm3(8, 8, 3);
    const dim3 gT3(32, 32, 3);

    // 1-2: conversions
    conv_xw<<<18432, blk, 0, stream>>>(x, xb, W_in, Winb);
    prep_wout<<<1024, blk, 0, stream>>>(W_out, Wouth, Woutl);

    // 3: z0 = x@W_in^T + b_in; u=z0 (fp32), AC_a=[11relu(z0) | z0+0.1*b1]
    gemm_bt<0><<<gBig, blk, 0, stream>>>(xb, Winb, u, AC_a, AC_a + 1024,
                                         nullptr, b_in, bs[0],
                                         8192, 1024, 2048, 2048, 2048,
                                         1024, 2048, 2048, 1.f, 0, 0, 0, 0);

    // 4: weight transposes (xb region is dead now)
    prep_w3<<<gT3, blk, 0, stream>>>(Ws[0], Ws[1], Ws[2], Wbf, Wtbf);
    // 5: Minv[z] -> Minv (ld1024) and Bcat[:, :1024] (ld2048)
    gemm_bt<1><<<gSm3, blk, 0, stream>>>(Wtbf, Wtbf, nullptr, Minv, Bcat,
                                         nullptr, nullptr, nullptr,
                                         1024, 1024, 1024, 1024, 1024,
                                         0, 1024, 2048, 1.f, M1, M1, M1, 2 * M1);
    // 6: Bcat[:, 1024:] = 0.1 * Minv @ W^T
    gemm_bt<2><<<gSm3, blk, 0, stream>>>(Minv, Wbf, nullptr, Bcat + 1024, nullptr,
                                         nullptr, nullptr, nullptr,
                                         1024, 1024, 1024, 1024, 1024,
                                         0, 2048, 0, C_DT, M1, M1, 2 * M1, 0);
    // 7: P = W @ Minv (Minv symmetric); also Ccat[:, :1024] = 0.1*P
    gemm_bt<2><<<gSm3, blk, 0, stream>>>(Wbf, Minv, nullptr, Pmat, Ccat,
                                         nullptr, nullptr, nullptr,
                                         1024, 1024, 1024, 1024, 1024,
                                         0, 1024, 2048, 1.f, M1, M1, M1, 2 * M1);
    // 8: Ccat[:, 1024:] = 0.01 * P @ W^T
    gemm_bt<2><<<gSm3, blk, 0, stream>>>(Pmat, Wbf, nullptr, Ccat + 1024, nullptr,
                                         nullptr, nullptr, nullptr,
                                         1024, 1024, 1024, 1024, 1024,
                                         0, 2048, 0, 0.01f, M1, M1, 2 * M1, 0);

    // 9-10: fused layers 0,1 (V in registers only; 4-phase counted schedule)
    gemm_layer8<<<gLay, blk512, 0, stream>>>(AC_a, Bcat, Ccat, u, AC_b, bs[0], bs[1]);
    gemm_layer8<<<gLay, blk512, 0, stream>>>(AC_b, Bcat + 2 * M1, Ccat + 2 * M1,
                                             u, AC_a, bs[1], bs[2]);
    // 11: layer 2 u-only: z = AC_a @ Ccat2^T - u - 0.1*b3 -> zh/zl
    gemm_bt<5><<<gBig, blk, 0, stream>>>(AC_a, Ccat + 4 * M1, nullptr, zh, zl,
                                         u, bs[2], nullptr,
                                         8192, 1024, 2048, 2048, 2048,
                                         1024, 1024, 1024, 1.f, 0, 0, 0, 0);

    // 12-13: logits (3-term split) + softmax
    gemm_split<<<gBig, blk, 0, stream>>>(zh, zl, Wouth, Woutl, logits, b_out,
                                         8192, 1024, 1024, 1000);
    softmax_rows<<<8192, blk, 0, stream>>>(logits, out);
}